// Round 5
// baseline (447.457 us; speedup 1.0000x reference)
//
#include <hip/hip_runtime.h>
#include <cstdint>
#include <cstddef>

typedef unsigned short u16;
typedef unsigned int   u32;

typedef short bf16x8 __attribute__((ext_vector_type(8)));
typedef float f32x4  __attribute__((ext_vector_type(4)));

// ---------------- helpers ----------------
__device__ __forceinline__ u16 f2bf(float f) {   // RNE f32 -> bf16
  u32 u = __float_as_uint(f);
  u += 0x7fffu + ((u >> 16) & 1u);
  return (u16)(u >> 16);
}
__device__ __forceinline__ float bflo(u32 w) { return __uint_as_float((w & 0xffffu) << 16); }
__device__ __forceinline__ float bfhi(u32 w) { return __uint_as_float(w & 0xffff0000u); }

// ---------------- fused f32 -> bf16 convert: inputs + Wi + Wo ----------------
// quads: inputs 4194304, Wi 131072, Wo 131072 -> 17408 blocks x 256 exactly.
__global__ __launch_bounds__(256)
void conv3_f32_bf16(const float* __restrict__ in, u16* __restrict__ a,
                    const float* __restrict__ wi, u16* __restrict__ wib,
                    const float* __restrict__ wo, u16* __restrict__ wob)
{
  long i = (long)blockIdx.x * 256 + threadIdx.x;
  const float* src; u16* dst;
  if (i < 4194304L) { src = in; dst = a; }
  else if (i < 4325376L) { i -= 4194304L; src = wi; dst = wib; }
  else { i -= 4325376L; if (i >= 131072L) return; src = wo; dst = wob; }
  float4 v = ((const float4*)src)[i];
  u32 lo = (u32)f2bf(v.x) | ((u32)f2bf(v.y) << 16);
  u32 hi = (u32)f2bf(v.z) | ((u32)f2bf(v.w) << 16);
  ((uint2*)dst)[i] = make_uint2(lo, hi);
}

// ---------------- LDS-free direct-fragment bf16 GEMM ------------------------
// C[m,n] = sum_k A[m,k] * W[n,k]  (A: MxK row-major, W: NxK row-major).
// Key fact: the mfma_f32_16x16x32_bf16 A/B fragment for lane L is the 16
// contiguous bytes A[(tile+L&15)*K + (L>>4)*8 .. +8) -- loadable directly from
// global with one dwordx4. No LDS, no barriers, no DMA bookkeeping.
// Block = 256 thr = 4 waves in 2x2 covering 128x128; the 2 waves sharing an
// A(B) panel sit on one CU -> L1 reuse halves L2 traffic.
// XCD swizzle: xcd = bid&7 (round-robin dispatch heuristic), per-XCD n-inner
// ordering -> each XCD's A slice (MT_XCD*128 rows) stays in its private L2.
template<int N, int K, int LOGNB, int MT_XCD, int OUT_BF16, int RELU>
__global__ __launch_bounds__(256, 3)
void gemm_direct(const u16* __restrict__ A, const u16* __restrict__ Bw,
                 const float* __restrict__ bias, void* __restrict__ Cout)
{
  const int tid  = threadIdx.x;
  const int lane = tid & 63;
  const int wave = tid >> 6;
  const int bid  = blockIdx.x;
  const int xcd  = bid & 7;
  const int s    = bid >> 3;
  const int m0 = (xcd * MT_XCD + (s >> LOGNB)) * 128;
  const int n0 = (s & ((1 << LOGNB) - 1)) * 128;
  const int wm = (wave & 1) * 64;
  const int wn = (wave >> 1) * 64;

  const int fr = lane & 15;        // fragment row within 16
  const int k8 = (lane >> 4) * 8;  // fragment k offset

  const u16* Ab = A  + (size_t)(m0 + wm + fr) * K + k8;
  const u16* Bb = Bw + (size_t)(n0 + wn + fr) * K + k8;

  f32x4 acc[4][4];
#pragma unroll
  for (int i = 0; i < 4; ++i)
#pragma unroll
    for (int j = 0; j < 4; ++j) acc[i][j] = f32x4{0.f, 0.f, 0.f, 0.f};

  bf16x8 af[2][4], bf[2][4];

#define LOADF(buf, kk)                                                         \
  {                                                                            \
    _Pragma("unroll")                                                          \
    for (int i = 0; i < 4; ++i) {                                              \
      af[buf][i] = *(const bf16x8*)(Ab + (size_t)(i * 16) * K + (kk));         \
      bf[buf][i] = *(const bf16x8*)(Bb + (size_t)(i * 16) * K + (kk));         \
    }                                                                          \
  }

  LOADF(0, 0)
#pragma unroll
  for (int kt = 0; kt < K; kt += 32) {
    const int cur = (kt >> 5) & 1;
    if (kt + 32 < K) LOADF(cur ^ 1, kt + 32)
#pragma unroll
    for (int mi = 0; mi < 4; ++mi)
#pragma unroll
      for (int ni = 0; ni < 4; ++ni)
        acc[mi][ni] = __builtin_amdgcn_mfma_f32_16x16x32_bf16(af[cur][mi], bf[cur][ni],
                                                              acc[mi][ni], 0, 0, 0);
  }
#undef LOADF

  // epilogue: C/D layout col=lane&15, row=(lane>>4)*4+reg  (R1/R2-validated)
  const int colL = lane & 15;
  const int rowQ = (lane >> 4) * 4;
#pragma unroll
  for (int mi = 0; mi < 4; ++mi) {
#pragma unroll
    for (int ni = 0; ni < 4; ++ni) {
      int col  = n0 + wn + ni * 16 + colL;
      int rowb = m0 + wm + mi * 16 + rowQ;
      float bv = bias[col];
#pragma unroll
      for (int r = 0; r < 4; ++r) {
        float v = acc[mi][ni][r] + bv;
        if (RELU) v = fmaxf(v, 0.f);
        size_t idx = (size_t)(rowb + r) * N + col;
        if (OUT_BF16) ((u16*)Cout)[idx] = f2bf(v);
        else          ((float*)Cout)[idx] = v;
      }
    }
  }
}

// ---------------- scan pass 1: per-chunk end state ----------------
__global__ __launch_bounds__(512)
void scan_chunk_end(const u16* __restrict__ u, const float* __restrict__ plog,
                    float2* __restrict__ e)
{
  const int j = threadIdx.x;   // channel 0..511
  const int c = blockIdx.x;    // chunk 0..31
  const int b = blockIdx.y;    // batch 0..7
  float vv  = expf(plog[j]);
  float th  = expf(plog[512 + j]);
  float mag = expf(-vv);
  float lr = mag * cosf(th), li = mag * sinf(th);
  const u32* up = (const u32*)u;
  size_t idx = (size_t)(b * 4096 + c * 128) * 512 + j;
  float hr = 0.f, hi = 0.f;
#pragma unroll 8
  for (int t = 0; t < 128; ++t) {
    u32 w = up[idx]; idx += 512;
    float ur = bflo(w), ui = bfhi(w);
    float nr = fmaf(lr, hr, fmaf(-li, hi, ur));
    float ni2 = fmaf(lr, hi, fmaf(li, hr, ui));
    hr = nr; hi = ni2;
  }
  e[(size_t)(b * 32 + c) * 512 + j] = make_float2(hr, hi);
}

// ---------------- scan pass 2 (fused carry + output) ----------------
__global__ __launch_bounds__(512)
void scan_out2(const u16* __restrict__ u, const float* __restrict__ plog,
               const float2* __restrict__ e, u16* __restrict__ xr)
{
  const int j = threadIdx.x;
  const int c = blockIdx.x;
  const int b = blockIdx.y;
  float vv  = expf(plog[j]);
  float th  = expf(plog[512 + j]);
  float gm  = expf(plog[1024 + j]);
  float mag = expf(-vv);
  float lr = mag * cosf(th), li = mag * sinf(th);

  // carry from chunk-end states (tiny, L2-resident)
  float Lm = expf(-128.f * vv);
  float La = 128.f * th;
  float Lr = Lm * cosf(La), Li = Lm * sinf(La);   // lambda^128
  float hr = 0.f, hi = 0.f;
  for (int i = 0; i < c; ++i) {
    float2 ec = e[(size_t)(b * 32 + i) * 512 + j];
    float nr = fmaf(Lr, hr, fmaf(-Li, hi, ec.x));
    float ni2 = fmaf(Lr, hi, fmaf(Li, hr, ec.y));
    hr = nr; hi = ni2;
  }

  const u32* up = (const u32*)u;
  size_t uidx = (size_t)(b * 4096 + c * 128) * 512 + j;
  size_t xidx = (size_t)(b * 4096 + c * 128) * 1024 + j;
#pragma unroll 4
  for (int t = 0; t < 128; ++t) {
    u32 w = up[uidx]; uidx += 512;
    float ur = bflo(w), ui = bfhi(w);
    float nr = fmaf(lr, hr, fmaf(-li, hi, ur));
    float ni2 = fmaf(lr, hi, fmaf(li, hr, ui));
    hr = nr; hi = ni2;
    xr[xidx]       = f2bf(gm * hr);
    xr[xidx + 512] = f2bf(gm * hi);
    xidx += 1024;
  }
}

// ---------------- launch ----------------
extern "C" void kernel_launch(void* const* d_in, const int* in_sizes, int n_in,
                              void* d_out, int out_size, void* d_ws, size_t ws_size,
                              hipStream_t stream)
{
  (void)in_sizes; (void)n_in; (void)out_size; (void)ws_size;
  const float* inputs = (const float*)d_in[0];
  const float* Wi     = (const float*)d_in[1];
  const float* bi     = (const float*)d_in[2];
  const float* Wo     = (const float*)d_in[3];
  const float* bo     = (const float*)d_in[4];
  const float* plog   = (const float*)d_in[5];

  char* ws = (char*)d_ws;
  u16*    xrA   = (u16*)(ws);                        // A_bf then xr_bf
  u16*    u_bf  = (u16*)(ws + 67108864ull);
  u16*    Wi_bf = (u16*)(ws + 134217728ull);
  u16*    Wo_bf = (u16*)(ws + 135266304ull);
  float2* e_b   = (float2*)(ws + 136314880ull);

  // 1) convert all three fp32 tensors to bf16 (one launch)
  conv3_f32_bf16<<<17408, 256, 0, stream>>>(inputs, xrA, Wi, Wi_bf, Wo, Wo_bf);

  // 2) u = X @ Wi^T + bi   (M=32768, N=1024, K=512), bf16 out
  //    256 m-blocks (32/XCD), 8 n-blocks -> 2048
  gemm_direct<1024, 512, 3, 32, 1, 0><<<2048, 256, 0, stream>>>(xrA, Wi_bf, bi, u_bf);

  // 3) chunked complex prefix scan + gamma, write xr (bf16) over A region
  scan_chunk_end<<<dim3(32, 8), 512, 0, stream>>>(u_bf, plog, e_b);
  scan_out2<<<dim3(32, 8), 512, 0, stream>>>(u_bf, plog, e_b, xrA);

  // 4) out = relu(xr @ Wo^T + bo)  (M=32768, N=512, K=1024), fp32 out
  //    256 m-blocks (32/XCD), 4 n-blocks -> 1024
  gemm_direct<512, 1024, 2, 32, 0, 1><<<1024, 256, 0, stream>>>(xrA, Wo_bf, bo, d_out);
}

// Round 6
// 272.512 us; speedup vs baseline: 1.6420x; 1.6420x over previous
//
#include <hip/hip_runtime.h>
#include <cstdint>
#include <cstddef>

typedef unsigned short u16;
typedef unsigned int   u32;

typedef short bf16x8 __attribute__((ext_vector_type(8)));
typedef float f32x4  __attribute__((ext_vector_type(4)));

// ---------------- helpers ----------------
__device__ __forceinline__ u16 f2bf(float f) {   // RNE f32 -> bf16
  u32 u = __float_as_uint(f);
  u += 0x7fffu + ((u >> 16) & 1u);
  return (u16)(u >> 16);
}
__device__ __forceinline__ float bflo(u32 w) { return __uint_as_float((w & 0xffffu) << 16); }
__device__ __forceinline__ float bfhi(u32 w) { return __uint_as_float(w & 0xffff0000u); }

#define GLB_AS(p) ((const __attribute__((address_space(1))) void*)(p))
#define LDS_AS(p) ((__attribute__((address_space(3))) void*)(p))

// ---------------- fused f32 -> bf16 convert: inputs + Wi + Wo ----------------
// quads: inputs 4194304, Wi 131072, Wo 131072 -> 17408 blocks x 256 exactly.
__global__ __launch_bounds__(256)
void conv3_f32_bf16(const float* __restrict__ in, u16* __restrict__ a,
                    const float* __restrict__ wi, u16* __restrict__ wib,
                    const float* __restrict__ wo, u16* __restrict__ wob)
{
  long i = (long)blockIdx.x * 256 + threadIdx.x;
  const float* src; u16* dst;
  if (i < 4194304L) { src = in; dst = a; }
  else if (i < 4325376L) { i -= 4194304L; src = wi; dst = wib; }
  else { i -= 4325376L; if (i >= 131072L) return; src = wo; dst = wob; }
  float4 v = ((const float4*)src)[i];
  u32 lo = (u32)f2bf(v.x) | ((u32)f2bf(v.y) << 16);
  u32 hi = (u32)f2bf(v.z) | ((u32)f2bf(v.w) << 16);
  ((uint2*)dst)[i] = make_uint2(lo, hi);
}

// ---------------- bf16 GEMM, 2-barrier LDS, BK=64, XCD-local -----------------
// C[m,n] = sum_k A[m,k] * W[n,k]  (A: MxK row-major, W: NxK row-major).
// Tile 128x128, BK=64 (32 KB LDS single-buffered -> halves barrier drains vs
// BK=32 while staying under the 64 KB occupancy cliff, m132). 256 thr = 4
// waves 2x2, each 64x64 via 2 k-halves of 16x16x32 MFMA (32 MFMA/wave-iter).
// XCD swizzle (validated R5: FETCH 264->43 MB): xcd=bid&7; per-XCD n-inner
// ordering keeps each XCD's 4 MB A slice resident in its private L2, so the
// global_load_lds drain is an L2-local ~300cyc, not a ~900cyc fabric trip.
// LDS layout: row = 8 granules of 16 B (128 B = all 32 banks). Granule at
// (row r, pos p) holds source k8 = p ^ (r&7); fragment (m, k8=c) reads pos
// c ^ (m&7) -> 16 lanes spread over all 8 positions (2-way = free, m136).
// DMA: instr i covers granules i*256+tid: 8 rows x 128 B contiguous segments.
template<int N, int K, int LOGNB, int OUT_BF16, int RELU>
__global__ __launch_bounds__(256, 4)
void gemm_xl(const u16* __restrict__ A, const u16* __restrict__ Bw,
             const float* __restrict__ bias, void* __restrict__ Cout)
{
  __shared__ __align__(16) u16 As[128 * 64];
  __shared__ __align__(16) u16 Bs[128 * 64];

  const int tid  = threadIdx.x;
  const int lane = tid & 63;
  const int wave = tid >> 6;
  const int bid  = blockIdx.x;
  const int xcd  = bid & 7;
  const int s    = bid >> 3;
  const int m0 = (xcd * 32 + (s >> LOGNB)) * 128;
  const int n0 = (s & ((1 << LOGNB) - 1)) * 128;
  const int wm = (wave & 1) * 64;
  const int wn = (wave >> 1) * 64;

  f32x4 acc[4][4];
#pragma unroll
  for (int i = 0; i < 4; ++i)
#pragma unroll
    for (int j = 0; j < 4; ++j) acc[i][j] = f32x4{0.f, 0.f, 0.f, 0.f};

  // DMA sources: instr i covers granule g = i*256 + tid
  const u16* Ap[4]; const u16* Bp[4]; int ldsOff[4];
#pragma unroll
  for (int i = 0; i < 4; ++i) {
    int g = i * 256 + tid;
    int r = g >> 3;
    int koff = ((g & 7) ^ (r & 7)) << 3;        // u16 units
    Ap[i] = A  + (size_t)(m0 + r) * K + koff;
    Bp[i] = Bw + (size_t)(n0 + r) * K + koff;
    ldsOff[i] = (i * 256 + wave * 64) * 8;      // wave-uniform base (u16 units)
  }

  // fragment offsets: [i][h]  (m = wm+i*16+fm, logical k8 = h*4+q)
  const int fm = lane & 15;
  const int q  = lane >> 4;
  int aoff[4][2], boff[4][2];
#pragma unroll
  for (int i = 0; i < 4; ++i) {
    int m = wm + i * 16 + fm;
    int n = wn + i * 16 + fm;
#pragma unroll
    for (int h = 0; h < 2; ++h) {
      aoff[i][h] = m * 64 + ((((h << 2) | q) ^ (m & 7)) << 3);
      boff[i][h] = n * 64 + ((((h << 2) | q) ^ (n & 7)) << 3);
    }
  }

  for (int kt = 0; kt < K; kt += 64) {
#pragma unroll
    for (int i = 0; i < 4; ++i)
      __builtin_amdgcn_global_load_lds(GLB_AS(Ap[i] + kt), LDS_AS(As + ldsOff[i]), 16, 0, 0);
#pragma unroll
    for (int i = 0; i < 4; ++i)
      __builtin_amdgcn_global_load_lds(GLB_AS(Bp[i] + kt), LDS_AS(Bs + ldsOff[i]), 16, 0, 0);
    __syncthreads();  // drain: tile visible

#pragma unroll
    for (int h = 0; h < 2; ++h) {
      bf16x8 af[4], bf[4];
#pragma unroll
      for (int i = 0; i < 4; ++i) { af[i] = *(const bf16x8*)&As[aoff[i][h]];
                                    bf[i] = *(const bf16x8*)&Bs[boff[i][h]]; }
#pragma unroll
      for (int mi = 0; mi < 4; ++mi)
#pragma unroll
        for (int ni = 0; ni < 4; ++ni)
          acc[mi][ni] = __builtin_amdgcn_mfma_f32_16x16x32_bf16(af[mi], bf[ni],
                                                                acc[mi][ni], 0, 0, 0);
    }
    __syncthreads();  // all reads done before next tile's DMA overwrites
  }

  // epilogue: C/D layout col=lane&15, row=(lane>>4)*4+reg  (validated R1-R5)
  const int colL = lane & 15;
  const int rowQ = (lane >> 4) * 4;
#pragma unroll
  for (int mi = 0; mi < 4; ++mi) {
#pragma unroll
    for (int ni = 0; ni < 4; ++ni) {
      int col  = n0 + wn + ni * 16 + colL;
      int rowb = m0 + wm + mi * 16 + rowQ;
      float bv = bias[col];
#pragma unroll
      for (int r = 0; r < 4; ++r) {
        float v = acc[mi][ni][r] + bv;
        if (RELU) v = fmaxf(v, 0.f);
        size_t idx = (size_t)(rowb + r) * N + col;
        if (OUT_BF16) ((u16*)Cout)[idx] = f2bf(v);
        else          ((float*)Cout)[idx] = v;
      }
    }
  }
}

// ---------------- scan pass 1: per-chunk end state ----------------
__global__ __launch_bounds__(512)
void scan_chunk_end(const u16* __restrict__ u, const float* __restrict__ plog,
                    float2* __restrict__ e)
{
  const int j = threadIdx.x;   // channel 0..511
  const int c = blockIdx.x;    // chunk 0..31
  const int b = blockIdx.y;    // batch 0..7
  float vv  = expf(plog[j]);
  float th  = expf(plog[512 + j]);
  float mag = expf(-vv);
  float lr = mag * cosf(th), li = mag * sinf(th);
  const u32* up = (const u32*)u;
  size_t idx = (size_t)(b * 4096 + c * 128) * 512 + j;
  float hr = 0.f, hi = 0.f;
#pragma unroll 8
  for (int t = 0; t < 128; ++t) {
    u32 w = up[idx]; idx += 512;
    float ur = bflo(w), ui = bfhi(w);
    float nr = fmaf(lr, hr, fmaf(-li, hi, ur));
    float ni2 = fmaf(lr, hi, fmaf(li, hr, ui));
    hr = nr; hi = ni2;
  }
  e[(size_t)(b * 32 + c) * 512 + j] = make_float2(hr, hi);
}

// ---------------- scan pass 2 (fused carry + output) ----------------
__global__ __launch_bounds__(512)
void scan_out2(const u16* __restrict__ u, const float* __restrict__ plog,
               const float2* __restrict__ e, u16* __restrict__ xr)
{
  const int j = threadIdx.x;
  const int c = blockIdx.x;
  const int b = blockIdx.y;
  float vv  = expf(plog[j]);
  float th  = expf(plog[512 + j]);
  float gm  = expf(plog[1024 + j]);
  float mag = expf(-vv);
  float lr = mag * cosf(th), li = mag * sinf(th);

  // carry from chunk-end states (tiny, L2-resident)
  float Lm = expf(-128.f * vv);
  float La = 128.f * th;
  float Lr = Lm * cosf(La), Li = Lm * sinf(La);   // lambda^128
  float hr = 0.f, hi = 0.f;
  for (int i = 0; i < c; ++i) {
    float2 ec = e[(size_t)(b * 32 + i) * 512 + j];
    float nr = fmaf(Lr, hr, fmaf(-Li, hi, ec.x));
    float ni2 = fmaf(Lr, hi, fmaf(Li, hr, ec.y));
    hr = nr; hi = ni2;
  }

  const u32* up = (const u32*)u;
  size_t uidx = (size_t)(b * 4096 + c * 128) * 512 + j;
  size_t xidx = (size_t)(b * 4096 + c * 128) * 1024 + j;
#pragma unroll 4
  for (int t = 0; t < 128; ++t) {
    u32 w = up[uidx]; uidx += 512;
    float ur = bflo(w), ui = bfhi(w);
    float nr = fmaf(lr, hr, fmaf(-li, hi, ur));
    float ni2 = fmaf(lr, hi, fmaf(li, hr, ui));
    hr = nr; hi = ni2;
    xr[xidx]       = f2bf(gm * hr);
    xr[xidx + 512] = f2bf(gm * hi);
    xidx += 1024;
  }
}

// ---------------- launch ----------------
extern "C" void kernel_launch(void* const* d_in, const int* in_sizes, int n_in,
                              void* d_out, int out_size, void* d_ws, size_t ws_size,
                              hipStream_t stream)
{
  (void)in_sizes; (void)n_in; (void)out_size; (void)ws_size;
  const float* inputs = (const float*)d_in[0];
  const float* Wi     = (const float*)d_in[1];
  const float* bi     = (const float*)d_in[2];
  const float* Wo     = (const float*)d_in[3];
  const float* bo     = (const float*)d_in[4];
  const float* plog   = (const float*)d_in[5];

  char* ws = (char*)d_ws;
  u16*    xrA   = (u16*)(ws);                        // A_bf then xr_bf
  u16*    u_bf  = (u16*)(ws + 67108864ull);
  u16*    Wi_bf = (u16*)(ws + 134217728ull);
  u16*    Wo_bf = (u16*)(ws + 135266304ull);
  float2* e_b   = (float2*)(ws + 136314880ull);

  // 1) convert all three fp32 tensors to bf16 (one launch)
  conv3_f32_bf16<<<17408, 256, 0, stream>>>(inputs, xrA, Wi, Wi_bf, Wo, Wo_bf);

  // 2) u = X @ Wi^T + bi   (M=32768, N=1024, K=512), bf16 out
  //    256 m-tiles (32/XCD) x 8 n-tiles
  gemm_xl<1024, 512, 3, 1, 0><<<2048, 256, 0, stream>>>(xrA, Wi_bf, bi, u_bf);

  // 3) chunked complex prefix scan + gamma, write xr (bf16) over A region
  scan_chunk_end<<<dim3(32, 8), 512, 0, stream>>>(u_bf, plog, e_b);
  scan_out2<<<dim3(32, 8), 512, 0, stream>>>(u_bf, plog, e_b, xrA);

  // 4) out = relu(xr @ Wo^T + bo)  (M=32768, N=512, K=1024), fp32 out
  //    256 m-tiles (32/XCD) x 4 n-tiles
  gemm_xl<512, 1024, 2, 0, 1><<<1024, 256, 0, stream>>>(xrA, Wo_bf, bo, d_out);
}

// Round 7
// 255.331 us; speedup vs baseline: 1.7525x; 1.0673x over previous
//
#include <hip/hip_runtime.h>
#include <cstdint>
#include <cstddef>

typedef unsigned short u16;
typedef unsigned int   u32;

typedef short bf16x8 __attribute__((ext_vector_type(8)));
typedef float f32x4  __attribute__((ext_vector_type(4)));

// ---------------- helpers ----------------
__device__ __forceinline__ u16 f2bf(float f) {   // RNE f32 -> bf16
  u32 u = __float_as_uint(f);
  u += 0x7fffu + ((u >> 16) & 1u);
  return (u16)(u >> 16);
}
__device__ __forceinline__ float bflo(u32 w) { return __uint_as_float((w & 0xffffu) << 16); }
__device__ __forceinline__ float bfhi(u32 w) { return __uint_as_float(w & 0xffff0000u); }

#define GLB_AS(p) ((const __attribute__((address_space(1))) void*)(p))
#define LDS_AS(p) ((__attribute__((address_space(3))) void*)(p))

// ---------------- fused f32 -> bf16 convert: inputs + Wi + Wo ----------------
// quads: inputs 4194304, Wi 131072, Wo 131072 -> 17408 blocks x 256 exactly.
__global__ __launch_bounds__(256)
void conv3_f32_bf16(const float* __restrict__ in, u16* __restrict__ a,
                    const float* __restrict__ wi, u16* __restrict__ wib,
                    const float* __restrict__ wo, u16* __restrict__ wob)
{
  long i = (long)blockIdx.x * 256 + threadIdx.x;
  const float* src; u16* dst;
  if (i < 4194304L) { src = in; dst = a; }
  else if (i < 4325376L) { i -= 4194304L; src = wi; dst = wib; }
  else { i -= 4325376L; if (i >= 131072L) return; src = wo; dst = wob; }
  float4 v = ((const float4*)src)[i];
  u32 lo = (u32)f2bf(v.x) | ((u32)f2bf(v.y) << 16);
  u32 hi = (u32)f2bf(v.z) | ((u32)f2bf(v.w) << 16);
  ((uint2*)dst)[i] = make_uint2(lo, hi);
}

// ---------------- bf16 GEMM, 256x128 tile, BK=32, 512 thr, XCD-local --------
// C[m,n] = sum_k A[m,k] * W[n,k]  (A: MxK row-major, W: NxK row-major).
// R6 post-mortem: all 128x128 variants stage 512 MB and land at 505 TF
// (7.5 TB/s staging-path ceiling). This tile stages (256+128)/(256*128) =
// 25% fewer bytes/FLOP -> 384 MB total. Per-wave geometry is byte-identical
// to the validated R2 kernel: 8 waves (4m x 2n) of 64x64, 4x4 acc, BK=32,
// R2's conflict-free granule swizzle (r>>1 XOR), same fragment maps.
// XCD swizzle kept (R5/R6-validated): xcd=bid&7, n-inner per XCD.
template<int N, int K, int LOGNB, int OUT_BF16, int RELU>
__global__ __launch_bounds__(512, 4)
void gemm_w2(const u16* __restrict__ A, const u16* __restrict__ Bw,
             const float* __restrict__ bias, void* __restrict__ Cout)
{
  __shared__ __align__(16) u16 As[256 * 32];   // 16 KB
  __shared__ __align__(16) u16 Bs[128 * 32];   //  8 KB

  const int tid  = threadIdx.x;
  const int lane = tid & 63;
  const int wave = tid >> 6;
  const int bid  = blockIdx.x;
  const int xcd  = bid & 7;
  const int s    = bid >> 3;
  const int m0 = (xcd * 16 + (s >> LOGNB)) * 256;
  const int n0 = (s & ((1 << LOGNB) - 1)) * 128;
  const int wm = (wave & 3) * 64;
  const int wn = (wave >> 2) * 64;

  f32x4 acc[4][4];
#pragma unroll
  for (int i = 0; i < 4; ++i)
#pragma unroll
    for (int j = 0; j < 4; ++j) acc[i][j] = f32x4{0.f, 0.f, 0.f, 0.f};

  // DMA staging (granule = 16 B; 4 granules per 32-k row; R2 swizzle):
  // A: 1024 granules -> 2 instrs; B: 512 granules -> 1 instr.
  const u16* Ap[2]; const u16* Bp; int ldsA[2]; int ldsB;
#pragma unroll
  for (int i = 0; i < 2; ++i) {
    int g = i * 512 + tid;
    int r = g >> 2;
    int koff = ((g & 3) ^ ((r >> 1) & 3)) << 3;
    Ap[i]   = A + (size_t)(m0 + r) * K + koff;
    ldsA[i] = (i * 512 + wave * 64) * 8;        // wave-uniform base (u16)
  }
  {
    int g = tid;
    int r = g >> 2;
    int koff = ((g & 3) ^ ((r >> 1) & 3)) << 3;
    Bp   = Bw + (size_t)(n0 + r) * K + koff;
    ldsB = (wave * 64) * 8;
  }

  // fragment granule offsets (R2-validated map)
  const int fm = lane & 15;
  const int q  = lane >> 4;
  int aoff[4], boff[4];
#pragma unroll
  for (int i = 0; i < 4; ++i) {
    int m = wm + i * 16 + fm;
    aoff[i] = (m * 4 + (q ^ ((m >> 1) & 3))) * 8;
    int n = wn + i * 16 + fm;
    boff[i] = (n * 4 + (q ^ ((n >> 1) & 3))) * 8;
  }

  for (int kt = 0; kt < K; kt += 32) {
    __builtin_amdgcn_global_load_lds(GLB_AS(Ap[0] + kt), LDS_AS(As + ldsA[0]), 16, 0, 0);
    __builtin_amdgcn_global_load_lds(GLB_AS(Ap[1] + kt), LDS_AS(As + ldsA[1]), 16, 0, 0);
    __builtin_amdgcn_global_load_lds(GLB_AS(Bp    + kt), LDS_AS(Bs + ldsB),    16, 0, 0);
    __syncthreads();  // drain: tile visible

    bf16x8 af[4], bf[4];
#pragma unroll
    for (int i = 0; i < 4; ++i) { af[i] = *(const bf16x8*)&As[aoff[i]];
                                  bf[i] = *(const bf16x8*)&Bs[boff[i]]; }
#pragma unroll
    for (int mi = 0; mi < 4; ++mi)
#pragma unroll
      for (int ni = 0; ni < 4; ++ni)
        acc[mi][ni] = __builtin_amdgcn_mfma_f32_16x16x32_bf16(af[mi], bf[ni],
                                                              acc[mi][ni], 0, 0, 0);
    __syncthreads();  // reads done before next tile's DMA overwrites
  }

  // epilogue: C/D layout col=lane&15, row=(lane>>4)*4+reg  (validated R1-R6)
  const int colL = lane & 15;
  const int rowQ = (lane >> 4) * 4;
#pragma unroll
  for (int mi = 0; mi < 4; ++mi) {
#pragma unroll
    for (int ni = 0; ni < 4; ++ni) {
      int col  = n0 + wn + ni * 16 + colL;
      int rowb = m0 + wm + mi * 16 + rowQ;
      float bv = bias[col];
#pragma unroll
      for (int r = 0; r < 4; ++r) {
        float v = acc[mi][ni][r] + bv;
        if (RELU) v = fmaxf(v, 0.f);
        size_t idx = (size_t)(rowb + r) * N + col;
        if (OUT_BF16) ((u16*)Cout)[idx] = f2bf(v);
        else          ((float*)Cout)[idx] = v;
      }
    }
  }
}

// ---------------- scan pass 1: per-chunk end state ----------------
__global__ __launch_bounds__(512)
void scan_chunk_end(const u16* __restrict__ u, const float* __restrict__ plog,
                    float2* __restrict__ e)
{
  const int j = threadIdx.x;   // channel 0..511
  const int c = blockIdx.x;    // chunk 0..31
  const int b = blockIdx.y;    // batch 0..7
  float vv  = expf(plog[j]);
  float th  = expf(plog[512 + j]);
  float mag = expf(-vv);
  float lr = mag * cosf(th), li = mag * sinf(th);
  const u32* up = (const u32*)u;
  size_t idx = (size_t)(b * 4096 + c * 128) * 512 + j;
  float hr = 0.f, hi = 0.f;
#pragma unroll 8
  for (int t = 0; t < 128; ++t) {
    u32 w = up[idx]; idx += 512;
    float ur = bflo(w), ui = bfhi(w);
    float nr = fmaf(lr, hr, fmaf(-li, hi, ur));
    float ni2 = fmaf(lr, hi, fmaf(li, hr, ui));
    hr = nr; hi = ni2;
  }
  e[(size_t)(b * 32 + c) * 512 + j] = make_float2(hr, hi);
}

// ---------------- scan pass 2 (fused carry + output) ----------------
__global__ __launch_bounds__(512)
void scan_out2(const u16* __restrict__ u, const float* __restrict__ plog,
               const float2* __restrict__ e, u16* __restrict__ xr)
{
  const int j = threadIdx.x;
  const int c = blockIdx.x;
  const int b = blockIdx.y;
  float vv  = expf(plog[j]);
  float th  = expf(plog[512 + j]);
  float gm  = expf(plog[1024 + j]);
  float mag = expf(-vv);
  float lr = mag * cosf(th), li = mag * sinf(th);

  // carry from chunk-end states (tiny, L2-resident)
  float Lm = expf(-128.f * vv);
  float La = 128.f * th;
  float Lr = Lm * cosf(La), Li = Lm * sinf(La);   // lambda^128
  float hr = 0.f, hi = 0.f;
  for (int i = 0; i < c; ++i) {
    float2 ec = e[(size_t)(b * 32 + i) * 512 + j];
    float nr = fmaf(Lr, hr, fmaf(-Li, hi, ec.x));
    float ni2 = fmaf(Lr, hi, fmaf(Li, hr, ec.y));
    hr = nr; hi = ni2;
  }

  const u32* up = (const u32*)u;
  size_t uidx = (size_t)(b * 4096 + c * 128) * 512 + j;
  size_t xidx = (size_t)(b * 4096 + c * 128) * 1024 + j;
#pragma unroll 4
  for (int t = 0; t < 128; ++t) {
    u32 w = up[uidx]; uidx += 512;
    float ur = bflo(w), ui = bfhi(w);
    float nr = fmaf(lr, hr, fmaf(-li, hi, ur));
    float ni2 = fmaf(lr, hi, fmaf(li, hr, ui));
    hr = nr; hi = ni2;
    xr[xidx]       = f2bf(gm * hr);
    xr[xidx + 512] = f2bf(gm * hi);
    xidx += 1024;
  }
}

// ---------------- launch ----------------
extern "C" void kernel_launch(void* const* d_in, const int* in_sizes, int n_in,
                              void* d_out, int out_size, void* d_ws, size_t ws_size,
                              hipStream_t stream)
{
  (void)in_sizes; (void)n_in; (void)out_size; (void)ws_size;
  const float* inputs = (const float*)d_in[0];
  const float* Wi     = (const float*)d_in[1];
  const float* bi     = (const float*)d_in[2];
  const float* Wo     = (const float*)d_in[3];
  const float* bo     = (const float*)d_in[4];
  const float* plog   = (const float*)d_in[5];

  char* ws = (char*)d_ws;
  u16*    xrA   = (u16*)(ws);                        // A_bf then xr_bf
  u16*    u_bf  = (u16*)(ws + 67108864ull);
  u16*    Wi_bf = (u16*)(ws + 134217728ull);
  u16*    Wo_bf = (u16*)(ws + 135266304ull);
  float2* e_b   = (float2*)(ws + 136314880ull);

  // 1) convert all three fp32 tensors to bf16 (one launch)
  conv3_f32_bf16<<<17408, 256, 0, stream>>>(inputs, xrA, Wi, Wi_bf, Wo, Wo_bf);

  // 2) u = X @ Wi^T + bi   (M=32768, N=1024, K=512), bf16 out
  //    128 m-tiles (16/XCD) x 8 n-tiles = 1024 blocks
  gemm_w2<1024, 512, 3, 1, 0><<<1024, 512, 0, stream>>>(xrA, Wi_bf, bi, u_bf);

  // 3) chunked complex prefix scan + gamma, write xr (bf16) over A region
  scan_chunk_end<<<dim3(32, 8), 512, 0, stream>>>(u_bf, plog, e_b);
  scan_out2<<<dim3(32, 8), 512, 0, stream>>>(u_bf, plog, e_b, xrA);

  // 4) out = relu(xr @ Wo^T + bo)  (M=32768, N=512, K=1024), fp32 out
  //    128 m-tiles (16/XCD) x 4 n-tiles = 512 blocks
  gemm_w2<512, 1024, 2, 0, 1><<<512, 512, 0, stream>>>(xrA, Wo_bf, bo, d_out);
}